// Round 11
// baseline (109.049 us; speedup 1.0000x reference)
//
#include <hip/hip_runtime.h>

typedef __attribute__((ext_vector_type(8))) short bf16x8;
typedef __attribute__((ext_vector_type(4))) float f32x4;
typedef __attribute__((ext_vector_type(4))) unsigned short u16x4;

__device__ __forceinline__ short f2bf(float f) {
  unsigned int u = __builtin_bit_cast(unsigned int, f);
  u += 0x7fffu + ((u >> 16) & 1u);  // RNE
  return (short)(u >> 16);
}

// ---------------- kernel 1: W^T bf16 prep ----------------
// wt[m][n][k] = W_m[k][n],  m in {q,k,v}, n<64, k<512  (r8 layout)
__global__ void prep_w(const float* __restrict__ Wq, const float* __restrict__ Wk,
                       const float* __restrict__ Wv, unsigned short* __restrict__ wt) {
  int idx = blockIdx.x * 256 + threadIdx.x;  // < 3*64*512
  int m = idx >> 15;
  int rem = idx & 32767;
  int n = rem >> 9;
  int k = rem & 511;
  const float* W = (m == 0) ? Wq : ((m == 1) ? Wk : Wv);
  wt[idx] = (unsigned short)f2bf(W[k * 64 + n]);
}

// ---------------- kernel 2: QKV projection (r8 structure, 16-row blocks) ----
// grid (2048, 3), 256 thr (4 waves), LDS 48 KB -> 3 blocks/CU (12 waves/CU).
// Block = 16 rows x 64 outcols, full K=512; wave w owns outcols w*16..+15,
// all waves share the 16 rows. Stage phase batch-issues 8 W bf16x8 + 8 x
// float4 per thread (batch small enough to survive regalloc; r8's 16-deep
// batch was split by the compiler at VGPR=88). Same verified swizzle
// formulas as r8. mode 0 (Q): scaled by 0.125*log2(e). mode 2 (V):
// transposed vt[b][dv][s], masked rows zeroed.
__global__ __launch_bounds__(256, 3) void proj_kernel(
    const float* __restrict__ qx, const float* __restrict__ kx, const float* __restrict__ vx,
    const unsigned short* __restrict__ wt, const int* __restrict__ mask,
    const float* __restrict__ bqp, const float* __restrict__ bkp, const float* __restrict__ bvp,
    unsigned short* __restrict__ qo, unsigned short* __restrict__ ko,
    unsigned short* __restrict__ vo) {
  __shared__ unsigned short xs[16 * 512];  // 16 KB x-tile bf16, swizzled; V bounce
  __shared__ unsigned short wl[64 * 256];  // 32 KB W^T half, swizzled

  const int mode = blockIdx.y;
  const float* x = (mode == 0) ? qx : ((mode == 1) ? kx : vx);
  const float* bias = (mode == 0) ? bqp : ((mode == 1) ? bkp : bvp);
  const unsigned short* wtm = wt + mode * (64 * 512);
  const float osc = (mode == 0) ? 0.18033688011112042f : 1.0f;  // 0.125*log2(e)

  const int tid = threadIdx.x;
  const int w = tid >> 6, lane = tid & 63;
  const int g = lane >> 4, ln = lane & 15;
  const int rowbase = blockIdx.x * 16;

  // ---- stage phase: batch-issue W half-0 + all x, then consume ----
  {
    bf16x8 wreg[8];
#pragma unroll
    for (int i = 0; i < 8; ++i) {  // W half 0 (L2-fast)
      int c = tid + i * 256;
      int n = c >> 5, kc = c & 31;
      wreg[i] = *reinterpret_cast<const bf16x8*>(wtm + n * 512 + kc * 8);
    }
    const float* src = x + (size_t)rowbase * 512;
    float4 xr[8];
#pragma unroll
    for (int i = 0; i < 8; ++i) {  // x: 16 rows x 512 f32, fully linear
      int idx = i * 256 + tid;  // f4-unit 0..2047 (128 per row)
      xr[i] = *reinterpret_cast<const float4*>(src + (size_t)idx * 4);
    }
#pragma unroll
    for (int i = 0; i < 8; ++i) {  // store W (waits only on W loads)
      int c = tid + i * 256;
      int n = c >> 5, kc = c & 31;
      int bo = (n * 512 + kc * 16) ^ ((n & 7) << 4);
      *reinterpret_cast<bf16x8*>(reinterpret_cast<char*>(wl) + bo) = wreg[i];
    }
#pragma unroll
    for (int i = 0; i < 8; ++i) {  // convert + store x
      int idx = i * 256 + tid;
      int row = idx >> 7, col4 = idx & 127;
      unsigned int pk0, pk1;
      asm("v_cvt_pk_bf16_f32 %0, %1, %2" : "=v"(pk0) : "v"(xr[i].x), "v"(xr[i].y));
      asm("v_cvt_pk_bf16_f32 %0, %1, %2" : "=v"(pk1) : "v"(xr[i].z), "v"(xr[i].w));
      union { unsigned int u[2]; u16x4 v; } pk;
      pk.u[0] = pk0;
      pk.u[1] = pk1;
      int u8 = col4 ^ ((row & 7) << 1);
      *reinterpret_cast<u16x4*>(reinterpret_cast<char*>(xs) + row * 1024 + u8 * 8) = pk.v;
    }
  }
  __syncthreads();

  const f32x4 fz = {0.f, 0.f, 0.f, 0.f};
  f32x4 acc = fz;

  const char* xrow_lds = reinterpret_cast<const char*>(xs) + ln * 1024;
  const int c7 = ln & 7;

#pragma unroll
  for (int t = 0; t < 16; ++t) {
    if (t == 8) {
      __syncthreads();  // all waves done with W half 0
      bf16x8 wreg[8];
#pragma unroll
      for (int i = 0; i < 8; ++i) {
        int c = tid + i * 256;
        int n = c >> 5, kc = c & 31;
        wreg[i] = *reinterpret_cast<const bf16x8*>(wtm + n * 512 + 256 + kc * 8);
      }
#pragma unroll
      for (int i = 0; i < 8; ++i) {
        int c = tid + i * 256;
        int n = c >> 5, kc = c & 31;
        int bo = (n * 512 + kc * 16) ^ ((n & 7) << 4);
        *reinterpret_cast<bf16x8*>(reinterpret_cast<char*>(wl) + bo) = wreg[i];
      }
      __syncthreads();
    }
    int v = t * 4 + g;  // 16B unit within row
    bf16x8 af = *reinterpret_cast<const bf16x8*>(xrow_lds + ((v ^ c7) * 16));
    int ks = t & 7;
    int n = w * 16 + ln;
    int bo = (n * 512 + ks * 64 + g * 16) ^ ((n & 7) << 4);
    bf16x8 bfrag = *reinterpret_cast<const bf16x8*>(reinterpret_cast<const char*>(wl) + bo);
    acc = __builtin_amdgcn_mfma_f32_16x16x32_bf16(af, bfrag, acc, 0, 0, 0);
  }

  const float bc = bias[w * 16 + ln];

  if (mode < 2) {
    unsigned short* o = (mode == 0) ? qo : ko;
#pragma unroll
    for (int r = 0; r < 4; ++r) {
      int row = rowbase + g * 4 + r;
      o[(size_t)row * 64 + w * 16 + ln] = (unsigned short)f2bf((acc[r] + bc) * osc);
    }
  } else {
    // V: bounce through xs (done reading it), emit vt[b][dv][s], mask-zeroed
    __syncthreads();
#pragma unroll
    for (int r = 0; r < 4; ++r)
      xs[(g * 4 + r) * 64 + w * 16 + ln] = (unsigned short)f2bf(acc[r] + bc);
    __syncthreads();
    int b = rowbase >> 12, s0 = rowbase & 4095;
    int dv = tid & 63, sc = tid >> 6;  // sc 0..3, 4 s each
    int sbase = s0 + sc * 4;
    const int* mrow = mask + b * 4096 + sbase;
    u16x4 pack;
#pragma unroll
    for (int j = 0; j < 4; ++j) {
      unsigned short vvv = xs[(sc * 4 + j) * 64 + dv];
      pack[j] = mrow[j] ? vvv : (unsigned short)0;
    }
    *reinterpret_cast<u16x4*>(vo + (size_t)(b * 64 + dv) * 4096 + sbase) = pack;
  }
}

// ---------------- kernel 3: flash attention (KV-split partials) ----------------
// grid (32, 8, 2), 256 thr (4 waves). Wave owns 32 q-rows (2 B-frags).
// blockIdx.z selects KV half; partial O (raw sums) and partial l written out;
// combine_kernel merges. No-max softmax makes partials purely additive.
#define KVBLK 128
#define NT 16

__global__ __launch_bounds__(256, 2) void attn_kernel(
    const unsigned short* __restrict__ qh, const unsigned short* __restrict__ kh,
    const unsigned short* __restrict__ vt, const int* __restrict__ mask,
    float* __restrict__ out0, float* __restrict__ out1,
    float* __restrict__ l0p, float* __restrict__ l1p) {
  __shared__ unsigned short kt[2][KVBLK * 64];  // 16 KB each, [kv][dk] swizzled
  __shared__ unsigned short vv[2][80 * 128];    // 20 KB each, 256B rows

  const int b = blockIdx.y;
  const int z = blockIdx.z;
  const int kv0 = z * (NT * KVBLK);
  float* __restrict__ optr = z ? out1 : out0;
  float* __restrict__ lptr = z ? l1p : l0p;
  const int qbase = blockIdx.x * 128;
  const int tid = threadIdx.x;
  const int w = tid >> 6, lane = tid & 63;
  const int g = lane >> 4, ln = lane & 15;

  // zero junk rows 65..79 of both vv buffers (read by the l-fragment MFMA)
  for (int i = tid; i < 15 * 128; i += 256) {
    vv[0][65 * 128 + i] = 0;
    vv[1][65 * 128 + i] = 0;
  }

  // Q B-frags (col = ln = q-row, k = 8g+j); qh pre-scaled by 0.125*log2e
  bf16x8 qa[2][2];
#pragma unroll
  for (int qf = 0; qf < 2; ++qf) {
    int row = qbase + w * 32 + qf * 16 + ln;
    const unsigned short* qp = qh + (size_t)(b * 4096 + row) * 64;
    qa[qf][0] = *reinterpret_cast<const bf16x8*>(qp + g * 8);
    qa[qf][1] = *reinterpret_cast<const bf16x8*>(qp + 32 + g * 8);
  }

  const f32x4 fz = {0.f, 0.f, 0.f, 0.f};
  f32x4 accO[2][5];
#pragma unroll
  for (int qf = 0; qf < 2; ++qf)
#pragma unroll
    for (int nf = 0; nf < 5; ++nf) accO[qf][nf] = fz;

  const unsigned short* khb = kh + (size_t)b * 4096 * 64;
  const unsigned short* vtb = vt + (size_t)b * 64 * 4096;

  // ---- staging (register prefetch -> swizzled LDS) ----
  bf16x8 kreg[4], vreg[4];
  int mreg = 0;
  auto issue = [&](int ti) {
    int kvbase = kv0 + ti * KVBLK;
#pragma unroll
    for (int i = 0; i < 4; ++i) {
      int c = tid + i * 256;  // V: dv = c>>4, phys kv start (c&15)*8
      vreg[i] = *reinterpret_cast<const bf16x8*>(vtb + (size_t)(c >> 4) * 4096 + kvbase + (c & 15) * 8);
      // K: row = c>>3 (kv), col16 = c&7
      kreg[i] = *reinterpret_cast<const bf16x8*>(khb + (size_t)(kvbase + (c >> 3)) * 64 + (c & 7) * 8);
    }
    if (tid < KVBLK) mreg = mask[b * 4096 + kvbase + tid];
  };
  auto commit = [&](int bs) {
#pragma unroll
    for (int i = 0; i < 4; ++i) {
      int c = tid + i * 256;
      // K swizzled store
      int kbo = ((c >> 3) * 128 + (c & 7) * 16) ^ (((c >> 3) & 7) << 4);
      *reinterpret_cast<bf16x8*>(reinterpret_cast<char*>(kt[bs]) + kbo) = kreg[i];
      // V tau-permuted store (two 8B halves)
      int dv = c >> 4;
      int P0 = (c & 15) * 8;
      int c2 = P0 >> 5, hh = (P0 >> 4) & 1, gg = (P0 >> 2) & 3;
      int x1 = 32 * c2 + 8 * gg + 4 * hh;
      int swz = (dv & 7) << 4;
      union { bf16x8 v; u16x4 h4[2]; } sp; sp.v = vreg[i];
      *reinterpret_cast<u16x4*>(reinterpret_cast<char*>(vv[bs]) + ((dv * 256 + 2 * x1) ^ swz)) = sp.h4[0];
      *reinterpret_cast<u16x4*>(reinterpret_cast<char*>(vv[bs]) + ((dv * 256 + 2 * x1 + 16) ^ swz)) = sp.h4[1];
    }
    if (tid < KVBLK) {
      int p = tid;
      int xx = 32 * (p >> 5) + 8 * ((p >> 2) & 3) + 4 * ((p >> 4) & 1) + (p & 3);
      vv[bs][64 * 128 + xx] = mreg ? (unsigned short)0x3F80 : (unsigned short)0;
    }
  };

  // ---- prologue ----
  issue(0);
  commit(0);
  __syncthreads();
  int cur = 0;

  for (int ti = 0; ti < NT; ++ti) {
    if (ti + 1 < NT) issue(ti + 1);  // loads in flight across compute

    // QK^T swapped: s{qf}[nf][r] = S[kv = nf*16+4g+r][q = qf*16+ln]
    f32x4 s0[8], s1[8];
#pragma unroll
    for (int nf = 0; nf < 8; ++nf) { s0[nf] = fz; s1[nf] = fz; }
    __builtin_amdgcn_s_setprio(1);
#pragma unroll
    for (int c2 = 0; c2 < 2; ++c2)
#pragma unroll
      for (int nf = 0; nf < 8; ++nf) {
        int kvr = nf * 16 + ln;
        int bo = (kvr * 128 + c2 * 64 + g * 16) ^ ((kvr & 7) << 4);
        bf16x8 kf = *reinterpret_cast<const bf16x8*>(reinterpret_cast<const char*>(kt[cur]) + bo);
        s0[nf] = __builtin_amdgcn_mfma_f32_16x16x32_bf16(kf, qa[0][c2], s0[nf], 0, 0, 0);
        s1[nf] = __builtin_amdgcn_mfma_f32_16x16x32_bf16(kf, qa[1][c2], s1[nf], 0, 0, 0);
      }
    __builtin_amdgcn_s_setprio(0);

    // p = exp2(s); pack to PV A-frag words (zero cross-lane via tau)
    unsigned int pw[2][4][4];
#pragma unroll
    for (int c2 = 0; c2 < 4; ++c2)
#pragma unroll
      for (int hh = 0; hh < 2; ++hh) {
        {
          float p0 = __builtin_exp2f(s0[2 * c2 + hh][0]);
          float p1 = __builtin_exp2f(s0[2 * c2 + hh][1]);
          float p2 = __builtin_exp2f(s0[2 * c2 + hh][2]);
          float p3 = __builtin_exp2f(s0[2 * c2 + hh][3]);
          unsigned int w0, w1;
          asm("v_cvt_pk_bf16_f32 %0, %1, %2" : "=v"(w0) : "v"(p0), "v"(p1));
          asm("v_cvt_pk_bf16_f32 %0, %1, %2" : "=v"(w1) : "v"(p2), "v"(p3));
          pw[0][c2][2 * hh] = w0;
          pw[0][c2][2 * hh + 1] = w1;
        }
        {
          float p0 = __builtin_exp2f(s1[2 * c2 + hh][0]);
          float p1 = __builtin_exp2f(s1[2 * c2 + hh][1]);
          float p2 = __builtin_exp2f(s1[2 * c2 + hh][2]);
          float p3 = __builtin_exp2f(s1[2 * c2 + hh][3]);
          unsigned int w0, w1;
          asm("v_cvt_pk_bf16_f32 %0, %1, %2" : "=v"(w0) : "v"(p0), "v"(p1));
          asm("v_cvt_pk_bf16_f32 %0, %1, %2" : "=v"(w1) : "v"(p2), "v"(p3));
          pw[1][c2][2 * hh] = w0;
          pw[1][c2][2 * hh + 1] = w1;
        }
      }

    // PV: O'[q][dv] += P·V  (A = in-reg P, B = vv frags; nf==4 -> l column)
    __builtin_amdgcn_s_setprio(1);
#pragma unroll
    for (int c2 = 0; c2 < 4; ++c2) {
      union { unsigned int u[4]; bf16x8 v; } pa0, pa1;
#pragma unroll
      for (int t = 0; t < 4; ++t) { pa0.u[t] = pw[0][c2][t]; pa1.u[t] = pw[1][c2][t]; }
#pragma unroll
      for (int nf = 0; nf < 5; ++nf) {
        int dvr = nf * 16 + ln;
        int bo = (dvr * 256 + c2 * 64 + g * 16) ^ ((dvr & 7) << 4);
        bf16x8 vb = *reinterpret_cast<const bf16x8*>(reinterpret_cast<const char*>(vv[cur]) + bo);
        accO[0][nf] = __builtin_amdgcn_mfma_f32_16x16x32_bf16(pa0.v, vb, accO[0][nf], 0, 0, 0);
        accO[1][nf] = __builtin_amdgcn_mfma_f32_16x16x32_bf16(pa1.v, vb, accO[1][nf], 0, 0, 0);
      }
    }
    __builtin_amdgcn_s_setprio(0);

    if (ti + 1 < NT) commit(cur ^ 1);
    __syncthreads();
    cur ^= 1;
  }

  // epilogue: raw partial O; l-frag valid at ln==0 lanes (dvr=64 column)
#pragma unroll
  for (int qf = 0; qf < 2; ++qf)
#pragma unroll
    for (int r = 0; r < 4; ++r) {
      int grow = b * 4096 + qbase + w * 32 + qf * 16 + g * 4 + r;
#pragma unroll
      for (int nf = 0; nf < 4; ++nf)
        optr[(size_t)grow * 64 + nf * 16 + ln] = accO[qf][nf][r];
      if (ln == 0) lptr[grow] = accO[qf][4][r];
    }
}

// ---------------- kernel 4: combine partials ----------------
// out = (O0 + O1) / (l0 + l1); 524288 float4s, grid 2048 x 256
__global__ __launch_bounds__(256) void combine_kernel(
    float* __restrict__ out, const float* __restrict__ po1,
    const float* __restrict__ l0p, const float* __restrict__ l1p) {
  int idx = blockIdx.x * 256 + threadIdx.x;
  int row = idx >> 4;  // 16 float4 per 64-col row
  float rl = 1.0f / (l0p[row] + l1p[row]);
  float4 a = reinterpret_cast<float4*>(out)[idx];
  float4 c = reinterpret_cast<const float4*>(po1)[idx];
  a.x = (a.x + c.x) * rl;
  a.y = (a.y + c.y) * rl;
  a.z = (a.z + c.z) * rl;
  a.w = (a.w + c.w) * rl;
  reinterpret_cast<float4*>(out)[idx] = a;
}

extern "C" void kernel_launch(void* const* d_in, const int* in_sizes, int n_in,
                              void* d_out, int out_size, void* d_ws, size_t ws_size,
                              hipStream_t stream) {
  const float* q = (const float*)d_in[0];
  const float* k = (const float*)d_in[1];
  const float* v = (const float*)d_in[2];
  const int* mask = (const int*)d_in[3];
  const float* Wq = (const float*)d_in[4];
  const float* bq = (const float*)d_in[5];
  const float* Wk = (const float*)d_in[6];
  const float* bk = (const float*)d_in[7];
  const float* Wv = (const float*)d_in[8];
  const float* bv = (const float*)d_in[9];

  char* wsb = (char*)d_ws;
  unsigned short* qh = (unsigned short*)(wsb);                    // 4 MiB
  unsigned short* kh = (unsigned short*)(wsb + (4u << 20));       // 4 MiB
  unsigned short* vt = (unsigned short*)(wsb + (8u << 20));       // 4 MiB
  unsigned short* wt = (unsigned short*)(wsb + (12u << 20));      // 192 KiB
  float* po1 = (float*)(wsb + (12u << 20) + 196608);              // 8 MiB
  float* l0p = (float*)(wsb + (12u << 20) + 196608 + (8u << 20)); // 128 KiB
  float* l1p = l0p + 32768;                                       // 128 KiB

  prep_w<<<384, 256, 0, stream>>>(Wq, Wk, Wv, wt);
  proj_kernel<<<dim3(2048, 3), 256, 0, stream>>>(q, k, v, wt, mask, bq, bk, bv, qh, kh, vt);
  attn_kernel<<<dim3(32, 8, 2), 256, 0, stream>>>(qh, kh, vt, mask,
                                                  (float*)d_out, po1, l0p, l1p);
  combine_kernel<<<2048, 256, 0, stream>>>((float*)d_out, po1, l0p, l1p);
}

// Round 13
// 106.444 us; speedup vs baseline: 1.0245x; 1.0245x over previous
//
#include <hip/hip_runtime.h>

typedef __attribute__((ext_vector_type(8))) short bf16x8;
typedef __attribute__((ext_vector_type(4))) float f32x4;
typedef __attribute__((ext_vector_type(4))) unsigned short u16x4;

__device__ __forceinline__ short f2bf(float f) {
  unsigned int u = __builtin_bit_cast(unsigned int, f);
  u += 0x7fffu + ((u >> 16) & 1u);  // RNE
  return (short)(u >> 16);
}

// ---------------- kernel 1: W^T bf16 prep ----------------
// wt[m][n][k] = W_m[k][n],  m in {q,k,v}, n<64, k<512
__global__ void prep_w(const float* __restrict__ Wq, const float* __restrict__ Wk,
                       const float* __restrict__ Wv, unsigned short* __restrict__ wt) {
  int idx = blockIdx.x * 256 + threadIdx.x;  // < 3*64*512
  int m = idx >> 15;
  int rem = idx & 32767;
  int n = rem >> 9;
  int k = rem & 511;
  const float* W = (m == 0) ? Wq : ((m == 1) ? Wk : Wv);
  wt[idx] = (unsigned short)f2bf(W[k * 64 + n]);
}

// ---------------- kernel 2: QKV projection (r8 body + XCD-contiguous swizzle) --
// 1D grid 3072, 256 thr (4 waves), LDS 64 KB -> 2 blocks/CU.
// Swizzle: xcd = bid&7, r0 = bid>>3, mode = r0>>7, rowbase = (xcd*128+(r0&127))*32.
// Each XCD streams a CONTIGUOUS 16 MB span of each input in row order (T1).
// Block = 32 rows x 64 outcols, full K=512; batch-issued staging (r8).
// V-epilogue: 32-row form (r12's 64-row transcription bug corrupted vt).
// mode 0 (Q): scaled by 0.125*log2(e). mode 2 (V): transposed vt[b][dv][s],
// masked rows zeroed.
__global__ __launch_bounds__(256, 2) void proj_kernel(
    const float* __restrict__ qx, const float* __restrict__ kx, const float* __restrict__ vx,
    const unsigned short* __restrict__ wt, const int* __restrict__ mask,
    const float* __restrict__ bqp, const float* __restrict__ bkp, const float* __restrict__ bvp,
    unsigned short* __restrict__ qo, unsigned short* __restrict__ ko,
    unsigned short* __restrict__ vo) {
  __shared__ unsigned short xs[32 * 512];  // 32 KB x-tile bf16, swizzled; V bounce
  __shared__ unsigned short wl[64 * 256];  // 32 KB W^T half, swizzled

  const int bid = blockIdx.x;
  const int xcd = bid & 7;
  const int r0 = bid >> 3;        // 0..383
  const int mode = r0 >> 7;       // 0..2
  const int rowblk = r0 & 127;    // 0..127
  const int rowbase = (xcd * 128 + rowblk) * 32;

  const float* x = (mode == 0) ? qx : ((mode == 1) ? kx : vx);
  const float* bias = (mode == 0) ? bqp : ((mode == 1) ? bkp : bvp);
  const unsigned short* wtm = wt + mode * (64 * 512);
  const float osc = (mode == 0) ? 0.18033688011112042f : 1.0f;  // 0.125*log2(e)

  const int tid = threadIdx.x;
  const int w = tid >> 6, lane = tid & 63;
  const int g = lane >> 4, ln = lane & 15;
  const int rh = w & 1, h = w >> 1;  // row-half, outcol-half

  // ---- stage phase: batch-issue all loads, then consume (r8 verbatim) ----
  {
    bf16x8 wreg[8];
#pragma unroll
    for (int i = 0; i < 8; ++i) {  // W half 0 (L2-fast)
      int c = tid + i * 256;
      int n = c >> 5, kc = c & 31;
      wreg[i] = *reinterpret_cast<const bf16x8*>(wtm + n * 512 + kc * 8);
    }
    const float* src = x + (size_t)rowbase * 512;
    float4 xr[16];
#pragma unroll
    for (int i = 0; i < 16; ++i) {  // x: 32 rows x 512 f32, fully linear
      int idx = i * 256 + tid;  // f4-unit 0..4095 (128 per row)
      xr[i] = *reinterpret_cast<const float4*>(src + (size_t)idx * 4);
    }
#pragma unroll
    for (int i = 0; i < 8; ++i) {  // store W (waits only on W loads)
      int c = tid + i * 256;
      int n = c >> 5, kc = c & 31;
      int bo = (n * 512 + kc * 16) ^ ((n & 7) << 4);
      *reinterpret_cast<bf16x8*>(reinterpret_cast<char*>(wl) + bo) = wreg[i];
    }
#pragma unroll
    for (int i = 0; i < 16; ++i) {  // convert + store x
      int idx = i * 256 + tid;
      int row = idx >> 7, col4 = idx & 127;
      unsigned int pk0, pk1;
      asm("v_cvt_pk_bf16_f32 %0, %1, %2" : "=v"(pk0) : "v"(xr[i].x), "v"(xr[i].y));
      asm("v_cvt_pk_bf16_f32 %0, %1, %2" : "=v"(pk1) : "v"(xr[i].z), "v"(xr[i].w));
      union { unsigned int u[2]; u16x4 v; } pk;
      pk.u[0] = pk0;
      pk.u[1] = pk1;
      int u8 = col4 ^ ((row & 7) << 1);
      *reinterpret_cast<u16x4*>(reinterpret_cast<char*>(xs) + row * 1024 + u8 * 8) = pk.v;
    }
  }
  __syncthreads();

  const f32x4 fz = {0.f, 0.f, 0.f, 0.f};
  f32x4 acc[2];
  acc[0] = fz;
  acc[1] = fz;

  const int lrow = rh * 16 + ln;
  const char* xrow_lds = reinterpret_cast<const char*>(xs) + lrow * 1024;
  const int c7 = lrow & 7;

#pragma unroll
  for (int t = 0; t < 16; ++t) {
    if (t == 8) {
      __syncthreads();  // all waves done with W half 0
      bf16x8 wreg[8];
#pragma unroll
      for (int i = 0; i < 8; ++i) {
        int c = tid + i * 256;
        int n = c >> 5, kc = c & 31;
        wreg[i] = *reinterpret_cast<const bf16x8*>(wtm + n * 512 + 256 + kc * 8);
      }
#pragma unroll
      for (int i = 0; i < 8; ++i) {
        int c = tid + i * 256;
        int n = c >> 5, kc = c & 31;
        int bo = (n * 512 + kc * 16) ^ ((n & 7) << 4);
        *reinterpret_cast<bf16x8*>(reinterpret_cast<char*>(wl) + bo) = wreg[i];
      }
      __syncthreads();
    }
    int v = t * 4 + g;  // 16B unit within row
    bf16x8 af = *reinterpret_cast<const bf16x8*>(xrow_lds + ((v ^ c7) * 16));
    int ks = t & 7;
#pragma unroll
    for (int nfi = 0; nfi < 2; ++nfi) {
      int n = h * 32 + nfi * 16 + ln;
      int bo = (n * 512 + ks * 64 + g * 16) ^ ((n & 7) << 4);
      bf16x8 bfrag = *reinterpret_cast<const bf16x8*>(reinterpret_cast<const char*>(wl) + bo);
      acc[nfi] = __builtin_amdgcn_mfma_f32_16x16x32_bf16(af, bfrag, acc[nfi], 0, 0, 0);
    }
  }

  float bc[2];
#pragma unroll
  for (int nfi = 0; nfi < 2; ++nfi) bc[nfi] = bias[h * 32 + nfi * 16 + ln];

  if (mode < 2) {
    unsigned short* o = (mode == 0) ? qo : ko;
#pragma unroll
    for (int nfi = 0; nfi < 2; ++nfi)
#pragma unroll
      for (int rr = 0; rr < 4; ++rr) {
        int row = rowbase + rh * 16 + g * 4 + rr;
        o[(size_t)row * 64 + h * 32 + nfi * 16 + ln] =
            (unsigned short)f2bf((acc[nfi][rr] + bc[nfi]) * osc);
      }
  } else {
    // V: bounce through xs (done reading it), emit vt[b][dv][s], mask-zeroed.
    // 32-row tile -> single 8-wide store per thread: rows sc*8+j (sc=tid>>6).
    __syncthreads();
#pragma unroll
    for (int nfi = 0; nfi < 2; ++nfi)
#pragma unroll
      for (int rr = 0; rr < 4; ++rr) {
        int srow = rh * 16 + g * 4 + rr;
        xs[srow * 64 + h * 32 + nfi * 16 + ln] = (unsigned short)f2bf(acc[nfi][rr] + bc[nfi]);
      }
    __syncthreads();
    int b = rowbase >> 12, s0 = rowbase & 4095;
    int dv = tid & 63, sc = tid >> 6;  // sc 0..3, 8 s each
    int sbase = s0 + sc * 8;
    const int* mrow = mask + b * 4096 + sbase;
    bf16x8 pack;
#pragma unroll
    for (int j = 0; j < 8; ++j) {
      short vvv = (short)xs[(sc * 8 + j) * 64 + dv];
      pack[j] = mrow[j] ? vvv : (short)0;
    }
    *reinterpret_cast<bf16x8*>(vo + (size_t)(b * 64 + dv) * 4096 + sbase) = pack;
  }
}

// ---------------- kernel 3: flash attention (KV-split partials) ----------------
// grid (32, 8, 2), 256 thr (4 waves). Wave owns 32 q-rows (2 B-frags).
// blockIdx.z selects KV half; partial O (raw sums) and partial l written out;
// combine_kernel merges. No-max softmax makes partials purely additive.
#define KVBLK 128
#define NT 16

__global__ __launch_bounds__(256, 2) void attn_kernel(
    const unsigned short* __restrict__ qh, const unsigned short* __restrict__ kh,
    const unsigned short* __restrict__ vt, const int* __restrict__ mask,
    float* __restrict__ out0, float* __restrict__ out1,
    float* __restrict__ l0p, float* __restrict__ l1p) {
  __shared__ unsigned short kt[2][KVBLK * 64];  // 16 KB each, [kv][dk] swizzled
  __shared__ unsigned short vv[2][80 * 128];    // 20 KB each, 256B rows

  const int b = blockIdx.y;
  const int z = blockIdx.z;
  const int kv0 = z * (NT * KVBLK);
  float* __restrict__ optr = z ? out1 : out0;
  float* __restrict__ lptr = z ? l1p : l0p;
  const int qbase = blockIdx.x * 128;
  const int tid = threadIdx.x;
  const int w = tid >> 6, lane = tid & 63;
  const int g = lane >> 4, ln = lane & 15;

  // zero junk rows 65..79 of both vv buffers (read by the l-fragment MFMA)
  for (int i = tid; i < 15 * 128; i += 256) {
    vv[0][65 * 128 + i] = 0;
    vv[1][65 * 128 + i] = 0;
  }

  // Q B-frags (col = ln = q-row, k = 8g+j); qh pre-scaled by 0.125*log2e
  bf16x8 qa[2][2];
#pragma unroll
  for (int qf = 0; qf < 2; ++qf) {
    int row = qbase + w * 32 + qf * 16 + ln;
    const unsigned short* qp = qh + (size_t)(b * 4096 + row) * 64;
    qa[qf][0] = *reinterpret_cast<const bf16x8*>(qp + g * 8);
    qa[qf][1] = *reinterpret_cast<const bf16x8*>(qp + 32 + g * 8);
  }

  const f32x4 fz = {0.f, 0.f, 0.f, 0.f};
  f32x4 accO[2][5];
#pragma unroll
  for (int qf = 0; qf < 2; ++qf)
#pragma unroll
    for (int nf = 0; nf < 5; ++nf) accO[qf][nf] = fz;

  const unsigned short* khb = kh + (size_t)b * 4096 * 64;
  const unsigned short* vtb = vt + (size_t)b * 64 * 4096;

  // ---- staging (register prefetch -> swizzled LDS) ----
  bf16x8 kreg[4], vreg[4];
  int mreg = 0;
  auto issue = [&](int ti) {
    int kvbase = kv0 + ti * KVBLK;
#pragma unroll
    for (int i = 0; i < 4; ++i) {
      int c = tid + i * 256;  // V: dv = c>>4, phys kv start (c&15)*8
      vreg[i] = *reinterpret_cast<const bf16x8*>(vtb + (size_t)(c >> 4) * 4096 + kvbase + (c & 15) * 8);
      // K: row = c>>3 (kv), col16 = c&7
      kreg[i] = *reinterpret_cast<const bf16x8*>(khb + (size_t)(kvbase + (c >> 3)) * 64 + (c & 7) * 8);
    }
    if (tid < KVBLK) mreg = mask[b * 4096 + kvbase + tid];
  };
  auto commit = [&](int bs) {
#pragma unroll
    for (int i = 0; i < 4; ++i) {
      int c = tid + i * 256;
      // K swizzled store
      int kbo = ((c >> 3) * 128 + (c & 7) * 16) ^ (((c >> 3) & 7) << 4);
      *reinterpret_cast<bf16x8*>(reinterpret_cast<char*>(kt[bs]) + kbo) = kreg[i];
      // V tau-permuted store (two 8B halves)
      int dv = c >> 4;
      int P0 = (c & 15) * 8;
      int c2 = P0 >> 5, hh = (P0 >> 4) & 1, gg = (P0 >> 2) & 3;
      int x1 = 32 * c2 + 8 * gg + 4 * hh;
      int swz = (dv & 7) << 4;
      union { bf16x8 v; u16x4 h4[2]; } sp; sp.v = vreg[i];
      *reinterpret_cast<u16x4*>(reinterpret_cast<char*>(vv[bs]) + ((dv * 256 + 2 * x1) ^ swz)) = sp.h4[0];
      *reinterpret_cast<u16x4*>(reinterpret_cast<char*>(vv[bs]) + ((dv * 256 + 2 * x1 + 16) ^ swz)) = sp.h4[1];
    }
    if (tid < KVBLK) {
      int p = tid;
      int xx = 32 * (p >> 5) + 8 * ((p >> 2) & 3) + 4 * ((p >> 4) & 1) + (p & 3);
      vv[bs][64 * 128 + xx] = mreg ? (unsigned short)0x3F80 : (unsigned short)0;
    }
  };

  // ---- prologue ----
  issue(0);
  commit(0);
  __syncthreads();
  int cur = 0;

  for (int ti = 0; ti < NT; ++ti) {
    if (ti + 1 < NT) issue(ti + 1);  // loads in flight across compute

    // QK^T swapped: s{qf}[nf][r] = S[kv = nf*16+4g+r][q = qf*16+ln]
    f32x4 s0[8], s1[8];
#pragma unroll
    for (int nf = 0; nf < 8; ++nf) { s0[nf] = fz; s1[nf] = fz; }
    __builtin_amdgcn_s_setprio(1);
#pragma unroll
    for (int c2 = 0; c2 < 2; ++c2)
#pragma unroll
      for (int nf = 0; nf < 8; ++nf) {
        int kvr = nf * 16 + ln;
        int bo = (kvr * 128 + c2 * 64 + g * 16) ^ ((kvr & 7) << 4);
        bf16x8 kf = *reinterpret_cast<const bf16x8*>(reinterpret_cast<const char*>(kt[cur]) + bo);
        s0[nf] = __builtin_amdgcn_mfma_f32_16x16x32_bf16(kf, qa[0][c2], s0[nf], 0, 0, 0);
        s1[nf] = __builtin_amdgcn_mfma_f32_16x16x32_bf16(kf, qa[1][c2], s1[nf], 0, 0, 0);
      }
    __builtin_amdgcn_s_setprio(0);

    // p = exp2(s); pack to PV A-frag words (zero cross-lane via tau)
    unsigned int pw[2][4][4];
#pragma unroll
    for (int c2 = 0; c2 < 4; ++c2)
#pragma unroll
      for (int hh = 0; hh < 2; ++hh) {
        {
          float p0 = __builtin_exp2f(s0[2 * c2 + hh][0]);
          float p1 = __builtin_exp2f(s0[2 * c2 + hh][1]);
          float p2 = __builtin_exp2f(s0[2 * c2 + hh][2]);
          float p3 = __builtin_exp2f(s0[2 * c2 + hh][3]);
          unsigned int w0, w1;
          asm("v_cvt_pk_bf16_f32 %0, %1, %2" : "=v"(w0) : "v"(p0), "v"(p1));
          asm("v_cvt_pk_bf16_f32 %0, %1, %2" : "=v"(w1) : "v"(p2), "v"(p3));
          pw[0][c2][2 * hh] = w0;
          pw[0][c2][2 * hh + 1] = w1;
        }
        {
          float p0 = __builtin_exp2f(s1[2 * c2 + hh][0]);
          float p1 = __builtin_exp2f(s1[2 * c2 + hh][1]);
          float p2 = __builtin_exp2f(s1[2 * c2 + hh][2]);
          float p3 = __builtin_exp2f(s1[2 * c2 + hh][3]);
          unsigned int w0, w1;
          asm("v_cvt_pk_bf16_f32 %0, %1, %2" : "=v"(w0) : "v"(p0), "v"(p1));
          asm("v_cvt_pk_bf16_f32 %0, %1, %2" : "=v"(w1) : "v"(p2), "v"(p3));
          pw[1][c2][2 * hh] = w0;
          pw[1][c2][2 * hh + 1] = w1;
        }
      }

    // PV: O'[q][dv] += P·V  (A = in-reg P, B = vv frags; nf==4 -> l column)
    __builtin_amdgcn_s_setprio(1);
#pragma unroll
    for (int c2 = 0; c2 < 4; ++c2) {
      union { unsigned int u[4]; bf16x8 v; } pa0, pa1;
#pragma unroll
      for (int t = 0; t < 4; ++t) { pa0.u[t] = pw[0][c2][t]; pa1.u[t] = pw[1][c2][t]; }
#pragma unroll
      for (int nf = 0; nf < 5; ++nf) {
        int dvr = nf * 16 + ln;
        int bo = (dvr * 256 + c2 * 64 + g * 16) ^ ((dvr & 7) << 4);
        bf16x8 vb = *reinterpret_cast<const bf16x8*>(reinterpret_cast<const char*>(vv[cur]) + bo);
        accO[0][nf] = __builtin_amdgcn_mfma_f32_16x16x32_bf16(pa0.v, vb, accO[0][nf], 0, 0, 0);
        accO[1][nf] = __builtin_amdgcn_mfma_f32_16x16x32_bf16(pa1.v, vb, accO[1][nf], 0, 0, 0);
      }
    }
    __builtin_amdgcn_s_setprio(0);

    if (ti + 1 < NT) commit(cur ^ 1);
    __syncthreads();
    cur ^= 1;
  }

  // epilogue: raw partial O; l-frag valid at ln==0 lanes (dvr=64 column)
#pragma unroll
  for (int qf = 0; qf < 2; ++qf)
#pragma unroll
    for (int r = 0; r < 4; ++r) {
      int grow = b * 4096 + qbase + w * 32 + qf * 16 + g * 4 + r;
#pragma unroll
      for (int nf = 0; nf < 4; ++nf)
        optr[(size_t)grow * 64 + nf * 16 + ln] = accO[qf][nf][r];
      if (ln == 0) lptr[grow] = accO[qf][4][r];
    }
}

// ---------------- kernel 4: combine partials ----------------
// out = (O0 + O1) / (l0 + l1); 524288 float4s, grid 2048 x 256
__global__ __launch_bounds__(256) void combine_kernel(
    float* __restrict__ out, const float* __restrict__ po1,
    const float* __restrict__ l0p, const float* __restrict__ l1p) {
  int idx = blockIdx.x * 256 + threadIdx.x;
  int row = idx >> 4;  // 16 float4 per 64-col row
  float rl = 1.0f / (l0p[row] + l1p[row]);
  float4 a = reinterpret_cast<float4*>(out)[idx];
  float4 c = reinterpret_cast<const float4*>(po1)[idx];
  a.x = (a.x + c.x) * rl;
  a.y = (a.y + c.y) * rl;
  a.z = (a.z + c.z) * rl;
  a.w = (a.w + c.w) * rl;
  reinterpret_cast<float4*>(out)[idx] = a;
}

extern "C" void kernel_launch(void* const* d_in, const int* in_sizes, int n_in,
                              void* d_out, int out_size, void* d_ws, size_t ws_size,
                              hipStream_t stream) {
  const float* q = (const float*)d_in[0];
  const float* k = (const float*)d_in[1];
  const float* v = (const float*)d_in[2];
  const int* mask = (const int*)d_in[3];
  const float* Wq = (const float*)d_in[4];
  const float* bq = (const float*)d_in[5];
  const float* Wk = (const float*)d_in[6];
  const float* bk = (const float*)d_in[7];
  const float* Wv = (const float*)d_in[8];
  const float* bv = (const float*)d_in[9];

  char* wsb = (char*)d_ws;
  unsigned short* qh = (unsigned short*)(wsb);                    // 4 MiB
  unsigned short* kh = (unsigned short*)(wsb + (4u << 20));       // 4 MiB
  unsigned short* vt = (unsigned short*)(wsb + (8u << 20));       // 4 MiB
  unsigned short* wt = (unsigned short*)(wsb + (12u << 20));      // 192 KiB
  float* po1 = (float*)(wsb + (12u << 20) + 196608);              // 8 MiB
  float* l0p = (float*)(wsb + (12u << 20) + 196608 + (8u << 20)); // 128 KiB
  float* l1p = l0p + 32768;                                       // 128 KiB

  prep_w<<<384, 256, 0, stream>>>(Wq, Wk, Wv, wt);
  proj_kernel<<<3072, 256, 0, stream>>>(q, k, v, wt, mask, bq, bk, bv, qh, kh, vt);
  attn_kernel<<<dim3(32, 8, 2), 256, 0, stream>>>(qh, kh, vt, mask,
                                                  (float*)d_out, po1, l0p, l1p);
  combine_kernel<<<2048, 256, 0, stream>>>((float*)d_out, po1, l0p, l1p);
}